// Round 8
// baseline (411.024 us; speedup 1.0000x reference)
//
#include <hip/hip_runtime.h>
#include <hip/hip_fp16.h>

#define NT      250000
#define NN      20000
#define RP      8
#define EMB     64
#define NCLS    16
#define NRELS   64
#define COLB    547       // ceil(NN*7/256)
#define REDB    64

// ---------------- A: LDS-row-tiled per-thread GEMV + softmax ----------------
__global__ __launch_bounds__(256) void k_gemv(
    const float* __restrict__ rm,
    const float* __restrict__ W1, const float* __restrict__ b1,
    const float* __restrict__ W2, const float* __restrict__ b2,
    float* __restrict__ l1, float* __restrict__ l2)    // [NT][8] each
{
    __shared__ float tile[256 * 20];
    int t = threadIdx.x;
    int base = blockIdx.x * 256;
    float a1[8], a2[8];
#pragma unroll
    for (int r = 0; r < 8; ++r) { a1[r] = b1[r]; a2[r] = b2[r]; }

#pragma unroll 1
    for (int kc = 0; kc < 4; ++kc) {
        __syncthreads();
#pragma unroll
        for (int q = 0; q < 4; ++q) {
            int i = q * 256 + t;
            int pl = i >> 2, j4 = i & 3;
            int p = base + pl;
            float4 v = make_float4(0.f, 0.f, 0.f, 0.f);
            if (p < NT) v = reinterpret_cast<const float4*>(rm)[(size_t)p * 16 + kc * 4 + j4];
            *reinterpret_cast<float4*>(&tile[pl * 20 + j4 * 4]) = v;
        }
        __syncthreads();
        float xr[16];
#pragma unroll
        for (int j4 = 0; j4 < 4; ++j4) {
            float4 v = *reinterpret_cast<const float4*>(&tile[t * 20 + j4 * 4]);
            xr[j4 * 4 + 0] = v.x; xr[j4 * 4 + 1] = v.y;
            xr[j4 * 4 + 2] = v.z; xr[j4 * 4 + 3] = v.w;
        }
#pragma unroll
        for (int kk = 0; kk < 16; ++kk) {
            float x = xr[kk];
            int k = kc * 16 + kk;
#pragma unroll
            for (int r = 0; r < 8; ++r) {
                a1[r] = fmaf(x, W1[k * 8 + r], a1[r]);
                a2[r] = fmaf(x, W2[k * 8 + r], a2[r]);
            }
        }
    }
    int p = base + t;
    if (p >= NT) return;
    float mx = a2[0];
#pragma unroll
    for (int r = 1; r < 8; ++r) mx = fmaxf(mx, a2[r]);
    float sm = 0.f;
#pragma unroll
    for (int r = 0; r < 8; ++r) { a2[r] = __expf(a2[r] - mx); sm += a2[r]; }
    float inv = 1.0f / sm;
#pragma unroll
    for (int r = 0; r < 8; ++r) a2[r] *= inv;
    float4* o1 = reinterpret_cast<float4*>(l1 + (size_t)p * 8);
    float4* o2 = reinterpret_cast<float4*>(l2 + (size_t)p * 8);
    o1[0] = make_float4(a1[0], a1[1], a1[2], a1[3]);
    o1[1] = make_float4(a1[4], a1[5], a1[6], a1[7]);
    o2[0] = make_float4(a2[0], a2[1], a2[2], a2[3]);
    o2[1] = make_float4(a2[4], a2[5], a2[6], a2[7]);
}

// ---------------- CSR offsets (hrow sorted by np.unique) ----------------
__global__ __launch_bounds__(256) void k_rowptr(
    const int* __restrict__ hrow, int* __restrict__ rowptr)
{
    int i = blockIdx.x * blockDim.x + threadIdx.x;
    if (i > NN) return;
    int lo = 0, hi = NT;
    while (lo < hi) { int mid = (lo + hi) >> 1; if (hrow[mid] < i) lo = mid + 1; else hi = mid; }
    rowptr[i] = lo;
}

// ---------------- CSC build ----------------
__global__ __launch_bounds__(256) void k_hist(
    const int* __restrict__ vcol, int* __restrict__ cnt)
{
    int p = blockIdx.x * blockDim.x + threadIdx.x;
    if (p < NT) atomicAdd(&cnt[vcol[p]], 1);
}

__global__ __launch_bounds__(1024) void k_scan(
    const int* __restrict__ cnt, int* __restrict__ cstart, int* __restrict__ cnt2)
{
    __shared__ int part[1024];
    int t = threadIdx.x;
    int base = t * 20;
    int local[20];
    int s = 0;
#pragma unroll
    for (int i = 0; i < 20; ++i) {
        int idx = base + i;
        int c = (idx < NN) ? cnt[idx] : 0;
        local[i] = s;
        s += c;
    }
    part[t] = s;
    __syncthreads();
    for (int off = 1; off < 1024; off <<= 1) {
        int v = (t >= off) ? part[t - off] : 0;
        __syncthreads();
        part[t] += v;
        __syncthreads();
    }
    int ebase = t ? part[t - 1] : 0;
#pragma unroll
    for (int i = 0; i < 20; ++i) {
        int idx = base + i;
        if (idx < NN) { cstart[idx] = ebase + local[i]; cnt2[idx] = ebase + local[i]; }
    }
    if (t == 1023) cstart[NN] = part[1023];
}

__global__ __launch_bounds__(256) void k_pos(
    const int* __restrict__ vcol, int* __restrict__ cnt2, int* __restrict__ cscidx)
{
    int p = blockIdx.x * blockDim.x + threadIdx.x;
    if (p >= NT) return;
    int o = vcol[p];
    int slot = atomicAdd(&cnt2[o], 1);
    cscidx[slot] = p;
}

// ---------------- colsum via CSC gather-reduce (divisor collisions via atomics) ----------------
__global__ __launch_bounds__(256) void k_colsum(
    const float* __restrict__ l1, const int* __restrict__ cstart,
    const int* __restrict__ cscidx, float* __restrict__ colsum)
{
    int bid = blockIdx.x;
    if (bid < COLB) {
        int tid = bid * 256 + threadIdx.x;
        if (tid < NN * 7) {
            int o = tid / 7;
            int r = tid - o * 7 + 1;
            int qb = cstart[o], qe = cstart[o + 1];
            float s = 0.f;
            for (int q = qb; q < qe; ++q)
                s += l1[(size_t)cscidx[q] * 8 + r];
            atomicAdd(&colsum[o * r], s);
        }
    } else {
        int b2 = bid - COLB;
        float s = 0.f;
        for (int i = b2 * 256 + threadIdx.x; i < NT; i += REDB * 256) s += l1[(size_t)i * 8];
        __shared__ float red[256];
        red[threadIdx.x] = s;
        __syncthreads();
        for (int off = 128; off > 0; off >>= 1) {
            if (threadIdx.x < off) red[threadIdx.x] += red[threadIdx.x + off];
            __syncthreads();
        }
        if (threadIdx.x == 0) atomicAdd(&colsum[0], red[0]);
    }
}

// ---------------- invert colsum in place ----------------
__global__ __launch_bounds__(256) void k_inv(float* __restrict__ cs)
{
    int i = blockIdx.x * blockDim.x + threadIdx.x;
    if (i < RP * NN) cs[i] = 1.0f / cs[i];
}

// ---------------- C1: per-object contributions (one wave per o) ----------------
// y[r] = ics[o*r] * w1[o*r][:] built once per o (kills the 448MB CSR gather);
// contrib[p] = sum_r l1[p][r] * y[r]  (fp16, coalesced 128B rows)
__global__ __launch_bounds__(256) void k_contrib(
    const float* __restrict__ l1, const float* __restrict__ ics,
    const int* __restrict__ cstart, const int* __restrict__ cscidx,
    const float* __restrict__ w1, __half* __restrict__ contrib)
{
    int o = (int)((blockIdx.x * blockDim.x + threadIdx.x) >> 6);
    int lane = threadIdx.x & 63;
    if (o >= NN) return;
    int qb = cstart[o], qe = cstart[o + 1];
    if (qb == qe) return;
    float y[8];
    y[0] = w1[lane] * ics[0];               // seg = o*0 = 0
#pragma unroll
    for (int r = 1; r < 8; ++r) {
        int seg = o * r;
        y[r] = w1[(size_t)seg * EMB + lane] * ics[seg];
    }
    for (int q = qb; q < qe; ++q) {
        int p = cscidx[q];
        const float4* lp4 = reinterpret_cast<const float4*>(l1 + (size_t)p * 8);
        float4 A = lp4[0], B = lp4[1];
        float v = A.x * y[0];
        v = fmaf(A.y, y[1], v); v = fmaf(A.z, y[2], v); v = fmaf(A.w, y[3], v);
        v = fmaf(B.x, y[4], v); v = fmaf(B.y, y[5], v);
        v = fmaf(B.z, y[6], v); v = fmaf(B.w, y[7], v);
        contrib[(size_t)p * EMB + lane] = __float2half(v);
    }
}

// ---------------- C2: h[s] = relu(bias + sum of contrib rows) (contiguous) ----------------
__global__ __launch_bounds__(256) void k_h(
    const __half* __restrict__ contrib, const int* __restrict__ rowptr,
    const float* __restrict__ bias1, float* __restrict__ h)
{
    int s = (int)((blockIdx.x * blockDim.x + threadIdx.x) >> 6);
    int lane = threadIdx.x & 63;
    if (s >= NN) return;
    int pb = rowptr[s], pe = rowptr[s + 1];
    float acc = 0.f;
    for (int p = pb; p < pe; ++p)
        acc += __half2float(contrib[(size_t)p * EMB + lane]);
    h[(size_t)s * EMB + lane] = fmaxf(acc + bias1[lane], 0.f);
}

// ---------------- D: per-s partial rows, NO atomics, NO big memset ----------------
// part[s][r-1][:] = sum_p l2[p][r]*h[o], partrs[s][r-1] = sum_p l2[p][r]
__global__ __launch_bounds__(256) void k_h2(
    const float* __restrict__ l2, const int* __restrict__ rowptr,
    const int* __restrict__ vcol, const float* __restrict__ h,
    float* __restrict__ part, float* __restrict__ partrs,
    float* __restrict__ Abuf0, float* __restrict__ rs0part)
{
    int s = (int)((blockIdx.x * blockDim.x + threadIdx.x) >> 6);
    int lane = threadIdx.x & 63;
    if (s >= NN) return;
    int pb = rowptr[s], pe = rowptr[s + 1];
    float acc[RP], rs[RP];
#pragma unroll
    for (int r = 0; r < RP; ++r) { acc[r] = 0.f; rs[r] = 0.f; }
    for (int p = pb; p < pe; ++p) {
        int o = vcol[p];
        float hv = h[(size_t)o * EMB + lane];
        const float* lp = l2 + (size_t)p * 8;
#pragma unroll
        for (int r = 0; r < RP; ++r) {
            float lv = lp[r];
            acc[r] = fmaf(lv, hv, acc[r]);
            rs[r] += lv;
        }
    }
    if (s == 0) {
        // every r maps to seg 0
        float a0 = 0.f, r0 = 0.f;
#pragma unroll
        for (int r = 0; r < RP; ++r) { a0 += acc[r]; r0 += rs[r]; }
        Abuf0[lane] = a0;
        if (lane == 0) rs0part[0] = r0;
    } else {
        Abuf0[(size_t)s * EMB + lane] = acc[0];      // r==0 -> seg 0
        if (lane == 0) rs0part[s] = rs[0];
#pragma unroll
        for (int r = 1; r < RP; ++r) {
            part[((size_t)s * 7 + (r - 1)) * EMB + lane] = acc[r];
            if (lane == 0) partrs[s * 7 + (r - 1)] = rs[r];
        }
    }
}

// ---------------- reduce seg-0 partials -> h0row, rs0 ----------------
__global__ __launch_bounds__(256) void k_red0(
    const float* __restrict__ Abuf0, const float* __restrict__ rs0part,
    float* __restrict__ h0row, float* __restrict__ rs0)
{
    __shared__ float red[256];
    if (blockIdx.x < 64) {
        int lane = threadIdx.x & 63, w = threadIdx.x >> 6;
        float sum = 0.f;
        for (int ss = blockIdx.x + 64 * w; ss < NN; ss += 256)
            sum += Abuf0[(size_t)ss * EMB + lane];
        red[threadIdx.x] = sum;
        __syncthreads();
        if (threadIdx.x < 64) {
            float v = red[threadIdx.x] + red[threadIdx.x + 64] +
                      red[threadIdx.x + 128] + red[threadIdx.x + 192];
            atomicAdd(&h0row[threadIdx.x], v);
        }
    } else {
        float sum = 0.f;
        for (int ssp = (int)threadIdx.x; ssp < NN; ssp += 256) sum += rs0part[ssp];
        red[threadIdx.x] = sum;
        __syncthreads();
        for (int off = 128; off > 0; off >>= 1) {
            if (threadIdx.x < off) red[threadIdx.x] += red[threadIdx.x + off];
            __syncthreads();
        }
        if (threadIdx.x == 0) atomicAdd(&rs0[0], red[0]);
    }
}

// ---------------- E: divisor-gather + /rowsum + einsum + bias2 ----------------
// h2[id k] = sum over (s,rr): s*rr == k of part[s][rr-1]  (k==0: seg0 row)
__global__ __launch_bounds__(1024) void k_logits(
    const float* __restrict__ part, const float* __restrict__ partrs,
    const float* __restrict__ h0row, const float* __restrict__ rs0,
    const float* __restrict__ w2, const float* __restrict__ bias2,
    float* __restrict__ out)
{
    __shared__ float w2s[RP * EMB * NCLS];   // 32 KB
    for (int i = threadIdx.x; i < RP * EMB * NCLS; i += 1024) w2s[i] = w2[i];
    __syncthreads();
    int wv = threadIdx.x >> 6, lane = threadIdx.x & 63;
    int n = blockIdx.x * 16 + wv;            // grid=1250 -> n < 20000 exactly
    int c = lane & 15, es = lane >> 4;
    float acc = 0.f;
#pragma unroll
    for (int rp = 0; rp <= 6; ++rp) {        // plane 7 provably zero
        int kk = rp * NN + n;
        float hsum = 0.f, rsum = 0.f;
#pragma unroll
        for (int rr = 1; rr <= 7; ++rr) {
            if (kk % rr == 0) {
                int s = kk / rr;
                if (s >= 1 && s < NN) {
                    hsum += part[((size_t)s * 7 + (rr - 1)) * EMB + lane];
                    rsum += partrs[s * 7 + (rr - 1)];
                }
            }
        }
        if (kk == 0) { hsum += h0row[lane]; rsum += rs0[0]; }
        float hv = (rsum > 0.f) ? hsum / fmaxf(rsum, 1e-6f) : 0.f;
#pragma unroll
        for (int eo = 0; eo < 16; ++eo) {
            float he = __shfl(hv, es * 16 + eo, 64);
            acc = fmaf(he, w2s[(rp * EMB + es * 16 + eo) * NCLS + c], acc);
        }
    }
    acc += __shfl_xor(acc, 16, 64);
    acc += __shfl_xor(acc, 32, 64);
    if (lane < 16) out[(size_t)n * NCLS + lane] = acc + bias2[lane];
}

extern "C" void kernel_launch(void* const* d_in, const int* in_sizes, int n_in,
                              void* d_out, int out_size, void* d_ws, size_t ws_size,
                              hipStream_t stream)
{
    const float* rm    = (const float*)d_in[0];
    const int*   hrow  = (const int*)d_in[1];   // sorted source nodes
    const int*   vcol  = (const int*)d_in[4];   // object nodes
    const float* W1    = (const float*)d_in[5];
    const float* b1    = (const float*)d_in[6];
    const float* W2    = (const float*)d_in[7];
    const float* b2    = (const float*)d_in[8];
    const float* w1    = (const float*)d_in[9];
    const float* w2    = (const float*)d_in[10];
    const float* bias1 = (const float*)d_in[11];
    const float* bias2 = (const float*)d_in[12];
    float* out = (float*)d_out;

    float* ws = (float*)d_ws;
    // layout (float offsets):
    float*  l1      = ws;                       // [0, 2.00M)   [NT][8]
    float*  l2      = ws + 2000000;             // [2.00M, 4.00M)
    int*    rowptr  = (int*)(ws + 4000000);     // 20001 ints
    float*  h0row   = ws + 4030000;             // 64 floats (seg0 h2 row)
    float*  rs0     = ws + 4030064;             // 1 float   (seg0 rowsum)
    float*  colsum  = ws + 4100000;             // 160000 (becomes inverse in-place)
    float*  h       = ws + 4320000;             // [4.32M, 5.60M)
    // CSC scratch aliases h region (dead before k_h writes h)
    int*    cnt     = (int*)(ws + 4320000);     // 20000
    int*    cstart  = cnt + 20000;              // 20001
    int*    cnt2    = cstart + 20001;           // 20000
    int*    cscidx  = cnt2 + 20000;             // 250000 (ends < 4.64M)
    // contrib (fp16) then part alias the same region (contrib dead after k_h)
    __half* contrib = (__half*)(ws + 5600000);  // NT*64 halfs = 8.0M float-slots
    float*  part    = ws + 5600000;             // [5.60M, 14.56M) 20000*7*64
    float*  partrs  = ws + 14560000;            // [14.56M, 14.70M) 140000
    // Abuf0/rs0part overlay l1 (dead after k_contrib)
    float*  Abuf0   = ws;                       // 1.28M
    float*  rs0part = ws + 1280000;             // 20000
    // total footprint: 14.70M floats = 58.8 MB

    hipMemsetAsync(colsum, 0, (size_t)160000 * sizeof(float), stream);
    hipMemsetAsync(h0row, 0, (size_t)65 * sizeof(float), stream);      // h0row+rs0
    hipMemsetAsync(cnt, 0, (size_t)20000 * sizeof(int), stream);

    k_rowptr <<<(NN + 256) / 256, 256, 0, stream>>>(hrow, rowptr);
    k_hist   <<<(NT + 255) / 256, 256, 0, stream>>>(vcol, cnt);
    k_scan   <<<1, 1024, 0, stream>>>(cnt, cstart, cnt2);
    k_pos    <<<(NT + 255) / 256, 256, 0, stream>>>(vcol, cnt2, cscidx);
    k_gemv   <<<(NT + 255) / 256, 256, 0, stream>>>(rm, W1, b1, W2, b2, l1, l2);
    k_colsum <<<COLB + REDB, 256, 0, stream>>>(l1, cstart, cscidx, colsum);
    k_inv    <<<(RP * NN + 255) / 256, 256, 0, stream>>>(colsum);
    k_contrib<<<(NN * 64) / 256, 256, 0, stream>>>(l1, colsum, cstart, cscidx, w1, contrib);
    k_h      <<<(NN * 64) / 256, 256, 0, stream>>>(contrib, rowptr, bias1, h);
    k_h2     <<<(NN * 64) / 256, 256, 0, stream>>>(l2, rowptr, vcol, h, part, partrs, Abuf0, rs0part);
    k_red0   <<<65, 256, 0, stream>>>(Abuf0, rs0part, h0row, rs0);
    k_logits <<<NN / 16, 1024, 0, stream>>>(part, partrs, h0row, rs0, w2, bias2, out);
}

// Round 9
// 287.640 us; speedup vs baseline: 1.4290x; 1.4290x over previous
//
#include <hip/hip_runtime.h>
#include <hip/hip_fp16.h>

#define NT      250000
#define NN      20000
#define RP      8
#define EMB     64
#define NCLS    16
#define NRELS   64
#define COLB    547       // ceil(NN*7/256)
#define REDB    64
#define SEGMAX  140000    // max written segment id + 1 (19999*7 = 139993)

// ---------------- A: LDS-row-tiled per-thread GEMV + softmax ----------------
__global__ __launch_bounds__(256) void k_gemv(
    const float* __restrict__ rm,
    const float* __restrict__ W1, const float* __restrict__ b1,
    const float* __restrict__ W2, const float* __restrict__ b2,
    float* __restrict__ l1, float* __restrict__ l2)    // [NT][8] each
{
    __shared__ float tile[256 * 20];
    int t = threadIdx.x;
    int base = blockIdx.x * 256;
    float a1[8], a2[8];
#pragma unroll
    for (int r = 0; r < 8; ++r) { a1[r] = b1[r]; a2[r] = b2[r]; }

#pragma unroll 1
    for (int kc = 0; kc < 4; ++kc) {
        __syncthreads();
#pragma unroll
        for (int q = 0; q < 4; ++q) {
            int i = q * 256 + t;
            int pl = i >> 2, j4 = i & 3;
            int p = base + pl;
            float4 v = make_float4(0.f, 0.f, 0.f, 0.f);
            if (p < NT) v = reinterpret_cast<const float4*>(rm)[(size_t)p * 16 + kc * 4 + j4];
            *reinterpret_cast<float4*>(&tile[pl * 20 + j4 * 4]) = v;
        }
        __syncthreads();
        float xr[16];
#pragma unroll
        for (int j4 = 0; j4 < 4; ++j4) {
            float4 v = *reinterpret_cast<const float4*>(&tile[t * 20 + j4 * 4]);
            xr[j4 * 4 + 0] = v.x; xr[j4 * 4 + 1] = v.y;
            xr[j4 * 4 + 2] = v.z; xr[j4 * 4 + 3] = v.w;
        }
#pragma unroll
        for (int kk = 0; kk < 16; ++kk) {
            float x = xr[kk];
            int k = kc * 16 + kk;
#pragma unroll
            for (int r = 0; r < 8; ++r) {
                a1[r] = fmaf(x, W1[k * 8 + r], a1[r]);
                a2[r] = fmaf(x, W2[k * 8 + r], a2[r]);
            }
        }
    }
    int p = base + t;
    if (p >= NT) return;
    float mx = a2[0];
#pragma unroll
    for (int r = 1; r < 8; ++r) mx = fmaxf(mx, a2[r]);
    float sm = 0.f;
#pragma unroll
    for (int r = 0; r < 8; ++r) { a2[r] = __expf(a2[r] - mx); sm += a2[r]; }
    float inv = 1.0f / sm;
#pragma unroll
    for (int r = 0; r < 8; ++r) a2[r] *= inv;
    float4* o1 = reinterpret_cast<float4*>(l1 + (size_t)p * 8);
    float4* o2 = reinterpret_cast<float4*>(l2 + (size_t)p * 8);
    o1[0] = make_float4(a1[0], a1[1], a1[2], a1[3]);
    o1[1] = make_float4(a1[4], a1[5], a1[6], a1[7]);
    o2[0] = make_float4(a2[0], a2[1], a2[2], a2[3]);
    o2[1] = make_float4(a2[4], a2[5], a2[6], a2[7]);
}

// ---------------- CSR offsets (hrow sorted by np.unique) ----------------
__global__ __launch_bounds__(256) void k_rowptr(
    const int* __restrict__ hrow, int* __restrict__ rowptr)
{
    int i = blockIdx.x * blockDim.x + threadIdx.x;
    if (i > NN) return;
    int lo = 0, hi = NT;
    while (lo < hi) { int mid = (lo + hi) >> 1; if (hrow[mid] < i) lo = mid + 1; else hi = mid; }
    rowptr[i] = lo;
}

// ---------------- CSC build ----------------
__global__ __launch_bounds__(256) void k_hist(
    const int* __restrict__ vcol, int* __restrict__ cnt)
{
    int p = blockIdx.x * blockDim.x + threadIdx.x;
    if (p < NT) atomicAdd(&cnt[vcol[p]], 1);
}

__global__ __launch_bounds__(1024) void k_scan(
    const int* __restrict__ cnt, int* __restrict__ cstart, int* __restrict__ cnt2)
{
    __shared__ int part[1024];
    int t = threadIdx.x;
    int base = t * 20;
    int local[20];
    int s = 0;
#pragma unroll
    for (int i = 0; i < 20; ++i) {
        int idx = base + i;
        int c = (idx < NN) ? cnt[idx] : 0;
        local[i] = s;
        s += c;
    }
    part[t] = s;
    __syncthreads();
    for (int off = 1; off < 1024; off <<= 1) {
        int v = (t >= off) ? part[t - off] : 0;
        __syncthreads();
        part[t] += v;
        __syncthreads();
    }
    int ebase = t ? part[t - 1] : 0;
#pragma unroll
    for (int i = 0; i < 20; ++i) {
        int idx = base + i;
        if (idx < NN) { cstart[idx] = ebase + local[i]; cnt2[idx] = ebase + local[i]; }
    }
    if (t == 1023) cstart[NN] = part[1023];
}

__global__ __launch_bounds__(256) void k_pos(
    const int* __restrict__ vcol, int* __restrict__ cnt2, int* __restrict__ cscidx)
{
    int p = blockIdx.x * blockDim.x + threadIdx.x;
    if (p >= NT) return;
    int o = vcol[p];
    int slot = atomicAdd(&cnt2[o], 1);
    cscidx[slot] = p;
}

// ---------------- colsum via CSC gather-reduce ----------------
__global__ __launch_bounds__(256) void k_colsum(
    const float* __restrict__ l1, const int* __restrict__ cstart,
    const int* __restrict__ cscidx, float* __restrict__ colsum)
{
    int bid = blockIdx.x;
    if (bid < COLB) {
        int tid = bid * 256 + threadIdx.x;
        if (tid < NN * 7) {
            int o = tid / 7;
            int r = tid - o * 7 + 1;
            int qb = cstart[o], qe = cstart[o + 1];
            float s = 0.f;
            for (int q = qb; q < qe; ++q)
                s += l1[(size_t)cscidx[q] * 8 + r];
            atomicAdd(&colsum[o * r], s);
        }
    } else {
        int b2 = bid - COLB;
        float s = 0.f;
        for (int i = b2 * 256 + threadIdx.x; i < NT; i += REDB * 256) s += l1[(size_t)i * 8];
        __shared__ float red[256];
        red[threadIdx.x] = s;
        __syncthreads();
        for (int off = 128; off > 0; off >>= 1) {
            if (threadIdx.x < off) red[threadIdx.x] += red[threadIdx.x + off];
            __syncthreads();
        }
        if (threadIdx.x == 0) atomicAdd(&colsum[0], red[0]);
    }
}

// ---------------- invert colsum in place ----------------
__global__ __launch_bounds__(256) void k_inv(float* __restrict__ cs)
{
    int i = blockIdx.x * blockDim.x + threadIdx.x;
    if (i < RP * NN) cs[i] = 1.0f / cs[i];
}

// ---------------- C1: per-object contributions (one wave per o) ----------------
// y[r] = ics[o*r] * w1[o*r][:] built once per o (w1 traffic 448MB -> 36MB);
// contrib[p] = sum_r l1[p][r] * y[r]  (fp16, coalesced 128B rows)
__global__ __launch_bounds__(256) void k_contrib(
    const float* __restrict__ l1, const float* __restrict__ ics,
    const int* __restrict__ cstart, const int* __restrict__ cscidx,
    const float* __restrict__ w1, __half* __restrict__ contrib)
{
    int o = (int)((blockIdx.x * blockDim.x + threadIdx.x) >> 6);
    int lane = threadIdx.x & 63;
    if (o >= NN) return;
    int qb = cstart[o], qe = cstart[o + 1];
    if (qb == qe) return;
    float y[8];
    y[0] = w1[lane] * ics[0];               // seg = o*0 = 0
#pragma unroll
    for (int r = 1; r < 8; ++r) {
        int seg = o * r;
        y[r] = w1[(size_t)seg * EMB + lane] * ics[seg];
    }
    for (int q = qb; q < qe; ++q) {
        int p = cscidx[q];
        const float4* lp4 = reinterpret_cast<const float4*>(l1 + (size_t)p * 8);
        float4 A = lp4[0], B = lp4[1];
        float v = A.x * y[0];
        v = fmaf(A.y, y[1], v); v = fmaf(A.z, y[2], v); v = fmaf(A.w, y[3], v);
        v = fmaf(B.x, y[4], v); v = fmaf(B.y, y[5], v);
        v = fmaf(B.z, y[6], v); v = fmaf(B.w, y[7], v);
        contrib[(size_t)p * EMB + lane] = __float2half(v);
    }
}

// ---------------- C2: h[s] = relu(bias + sum of contrib rows) (contiguous) ----------------
__global__ __launch_bounds__(256) void k_h(
    const __half* __restrict__ contrib, const int* __restrict__ rowptr,
    const float* __restrict__ bias1, float* __restrict__ h)
{
    int s = (int)((blockIdx.x * blockDim.x + threadIdx.x) >> 6);
    int lane = threadIdx.x & 63;
    if (s >= NN) return;
    int pb = rowptr[s], pe = rowptr[s + 1];
    float acc = 0.f;
    for (int p = pb; p < pe; ++p)
        acc += __half2float(contrib[(size_t)p * EMB + lane]);
    h[(size_t)s * EMB + lane] = fmaxf(acc + bias1[lane], 0.f);
}

// ---------------- D: one wave per node s; atomic scatter (depth<=7) [round-7 proven] ----------------
__global__ __launch_bounds__(256) void k_h2(
    const float* __restrict__ l2, const int* __restrict__ rowptr,
    const int* __restrict__ vcol, const float* __restrict__ h,
    float* __restrict__ h2raw, float* __restrict__ rowsum,
    float* __restrict__ Abuf0, float* __restrict__ rs0part)
{
    int wave = (int)((blockIdx.x * blockDim.x + threadIdx.x) >> 6);
    int lane = threadIdx.x & 63;
    if (wave >= NN) return;
    int s = wave;
    int pb = rowptr[s], pe = rowptr[s + 1];
    float acc[RP], rs[RP];
#pragma unroll
    for (int r = 0; r < RP; ++r) { acc[r] = 0.f; rs[r] = 0.f; }
    for (int p = pb; p < pe; ++p) {
        int o = vcol[p];
        float hv = h[(size_t)o * EMB + lane];
        const float* lp = l2 + (size_t)p * 8;
#pragma unroll
        for (int r = 0; r < RP; ++r) {
            float lv = lp[r];
            acc[r] = fmaf(lv, hv, acc[r]);
            rs[r] += lv;
        }
    }
    if (s == 0) {
        float a0 = 0.f, r0 = 0.f;
#pragma unroll
        for (int r = 0; r < RP; ++r) { a0 += acc[r]; r0 += rs[r]; }
        Abuf0[lane] = a0;
        if (lane == 0) rs0part[0] = r0;
    } else {
        Abuf0[(size_t)s * EMB + lane] = acc[0];
        if (lane == 0) rs0part[s] = rs[0];
#pragma unroll
        for (int r = 1; r < RP; ++r) {
            int seg = s * r;
            atomicAdd(&h2raw[(size_t)seg * EMB + lane], acc[r]);
            if (lane == 0) atomicAdd(&rowsum[seg], rs[r]);
        }
    }
}

// ---------------- reduce seg-0 partials ----------------
__global__ __launch_bounds__(256) void k_red0(
    const float* __restrict__ Abuf0, const float* __restrict__ rs0part,
    float* __restrict__ h2raw, float* __restrict__ rowsum)
{
    __shared__ float red[256];
    if (blockIdx.x < 64) {
        int lane = threadIdx.x & 63, w = threadIdx.x >> 6;
        float sum = 0.f;
        for (int ss = blockIdx.x + 64 * w; ss < NN; ss += 256)
            sum += Abuf0[(size_t)ss * EMB + lane];
        red[threadIdx.x] = sum;
        __syncthreads();
        if (threadIdx.x < 64) {
            float v = red[threadIdx.x] + red[threadIdx.x + 64] +
                      red[threadIdx.x + 128] + red[threadIdx.x + 192];
            atomicAdd(&h2raw[threadIdx.x], v);
        }
    } else {
        float sum = 0.f;
        for (int ssp = (int)threadIdx.x; ssp < NN; ssp += 256) sum += rs0part[ssp];
        red[threadIdx.x] = sum;
        __syncthreads();
        for (int off = 128; off > 0; off >>= 1) {
            if (threadIdx.x < off) red[threadIdx.x] += red[threadIdx.x + off];
            __syncthreads();
        }
        if (threadIdx.x == 0) atomicAdd(&rowsum[0], red[0]);
    }
}

// ---------------- E: fused /rowsum + einsum + bias2 (r=7 plane provably zero) ----------------
__global__ __launch_bounds__(1024) void k_logits(
    const float* __restrict__ h2raw, const float* __restrict__ rowsum,
    const float* __restrict__ w2, const float* __restrict__ bias2,
    float* __restrict__ out)
{
    __shared__ float w2s[RP * EMB * NCLS];   // 32 KB
    for (int i = threadIdx.x; i < RP * EMB * NCLS; i += 1024) w2s[i] = w2[i];
    __syncthreads();
    int wv = threadIdx.x >> 6, lane = threadIdx.x & 63;
    int n = blockIdx.x * 16 + wv;            // grid=1250 -> n < 20000 exactly
    int c = lane & 15, es = lane >> 4;
    float acc = 0.f;
#pragma unroll
    for (int r = 0; r <= 6; ++r) {
        size_t k = (size_t)r * NN + n;
        float hv = h2raw[k * EMB + lane] / fmaxf(rowsum[k], 1e-6f);
#pragma unroll
        for (int eo = 0; eo < 16; ++eo) {
            float he = __shfl(hv, es * 16 + eo, 64);
            acc = fmaf(he, w2s[(r * EMB + es * 16 + eo) * NCLS + c], acc);
        }
    }
    acc += __shfl_xor(acc, 16, 64);
    acc += __shfl_xor(acc, 32, 64);
    if (lane < 16) out[(size_t)n * NCLS + lane] = acc + bias2[lane];
}

extern "C" void kernel_launch(void* const* d_in, const int* in_sizes, int n_in,
                              void* d_out, int out_size, void* d_ws, size_t ws_size,
                              hipStream_t stream)
{
    const float* rm    = (const float*)d_in[0];
    const int*   hrow  = (const int*)d_in[1];   // sorted source nodes
    const int*   vcol  = (const int*)d_in[4];   // object nodes
    const float* W1    = (const float*)d_in[5];
    const float* b1    = (const float*)d_in[6];
    const float* W2    = (const float*)d_in[7];
    const float* b2    = (const float*)d_in[8];
    const float* w1    = (const float*)d_in[9];
    const float* w2    = (const float*)d_in[10];
    const float* bias1 = (const float*)d_in[11];
    const float* bias2 = (const float*)d_in[12];
    float* out = (float*)d_out;

    float* ws      = (float*)d_ws;
    float*  l1      = ws;                       // [0, 2.00M)   [NT][8]
    float*  l2      = ws + 2000000;             // [2.00M, 4.00M)
    float*  colsum  = ws + 4000000;             // 160,000 (inverted in place)
    float*  rowsum  = ws + 4160000;             // 160,000
    float*  h       = ws + 4320000;             // [4.32M, 5.60M)
    float*  h2raw   = ws + 5600000;             // [5.60M, 15.84M)
    int*    rowptr  = (int*)(ws + 15840000);    // 20,001 ints
    // CSC scratch aliases h region (h written only by k_h, after k_contrib reads CSC)
    int* cnt    = (int*)(ws + 4320000);         // 20,000
    int* cstart = cnt + 20000;                  // 20,001
    int* cnt2   = cstart + 20001;               // 20,000
    int* cscidx = cnt2 + 20000;                 // 250,000
    // contrib (fp16, 8M float-slots) aliases h2raw's head; h2raw memset runs AFTER k_h
    __half* contrib = (__half*)(ws + 5600000);
    // Abuf0/rs0part overlay l1 (l1 dead after k_contrib)
    float* Abuf0   = ws;                        // 1.28M
    float* rs0part = ws + 1280000;              // 20,000

    hipMemsetAsync(colsum, 0, (size_t)320000 * sizeof(float), stream);   // colsum+rowsum
    hipMemsetAsync(cnt, 0, (size_t)20000 * sizeof(int), stream);

    k_rowptr <<<(NN + 256) / 256, 256, 0, stream>>>(hrow, rowptr);
    k_hist   <<<(NT + 255) / 256, 256, 0, stream>>>(vcol, cnt);
    k_scan   <<<1, 1024, 0, stream>>>(cnt, cstart, cnt2);
    k_pos    <<<(NT + 255) / 256, 256, 0, stream>>>(vcol, cnt2, cscidx);
    k_gemv   <<<(NT + 255) / 256, 256, 0, stream>>>(rm, W1, b1, W2, b2, l1, l2);
    k_colsum <<<COLB + REDB, 256, 0, stream>>>(l1, cstart, cscidx, colsum);
    k_inv    <<<(RP * NN + 255) / 256, 256, 0, stream>>>(colsum);
    k_contrib<<<(NN * 64) / 256, 256, 0, stream>>>(l1, colsum, cstart, cscidx, w1, contrib);
    k_h      <<<(NN * 64) / 256, 256, 0, stream>>>(contrib, rowptr, bias1, h);
    // h2raw zero AFTER k_h (contrib alias dead), before k_h2 accumulates
    hipMemsetAsync(h2raw, 0, (size_t)SEGMAX * EMB * sizeof(float), stream);
    k_h2     <<<(NN * 64) / 256, 256, 0, stream>>>(l2, rowptr, vcol, h, h2raw, rowsum, Abuf0, rs0part);
    k_red0   <<<65, 256, 0, stream>>>(Abuf0, rs0part, h2raw, rowsum);
    k_logits <<<NN / 16, 1024, 0, stream>>>(h2raw, rowsum, w2, bias2, out);
}

// Round 10
// 261.816 us; speedup vs baseline: 1.5699x; 1.0986x over previous
//
#include <hip/hip_runtime.h>
#include <hip/hip_fp16.h>

#define NT      250000
#define NN      20000
#define RP      8
#define EMB     64
#define NCLS    16
#define NRELS   64
#define COLB    547       // ceil(NN*7/256)
#define REDB    64
#define KMAX    140000    // max segment id + 1 (19999*7 = 139993)

// ---------------- A: LDS-row-tiled per-thread GEMV + softmax ----------------
__global__ __launch_bounds__(256) void k_gemv(
    const float* __restrict__ rm,
    const float* __restrict__ W1, const float* __restrict__ b1,
    const float* __restrict__ W2, const float* __restrict__ b2,
    float* __restrict__ l1, float* __restrict__ l2)    // [NT][8] each
{
    __shared__ float tile[256 * 20];
    int t = threadIdx.x;
    int base = blockIdx.x * 256;
    float a1[8], a2[8];
#pragma unroll
    for (int r = 0; r < 8; ++r) { a1[r] = b1[r]; a2[r] = b2[r]; }

#pragma unroll 1
    for (int kc = 0; kc < 4; ++kc) {
        __syncthreads();
#pragma unroll
        for (int q = 0; q < 4; ++q) {
            int i = q * 256 + t;
            int pl = i >> 2, j4 = i & 3;
            int p = base + pl;
            float4 v = make_float4(0.f, 0.f, 0.f, 0.f);
            if (p < NT) v = reinterpret_cast<const float4*>(rm)[(size_t)p * 16 + kc * 4 + j4];
            *reinterpret_cast<float4*>(&tile[pl * 20 + j4 * 4]) = v;
        }
        __syncthreads();
        float xr[16];
#pragma unroll
        for (int j4 = 0; j4 < 4; ++j4) {
            float4 v = *reinterpret_cast<const float4*>(&tile[t * 20 + j4 * 4]);
            xr[j4 * 4 + 0] = v.x; xr[j4 * 4 + 1] = v.y;
            xr[j4 * 4 + 2] = v.z; xr[j4 * 4 + 3] = v.w;
        }
#pragma unroll
        for (int kk = 0; kk < 16; ++kk) {
            float x = xr[kk];
            int k = kc * 16 + kk;
#pragma unroll
            for (int r = 0; r < 8; ++r) {
                a1[r] = fmaf(x, W1[k * 8 + r], a1[r]);
                a2[r] = fmaf(x, W2[k * 8 + r], a2[r]);
            }
        }
    }
    int p = base + t;
    if (p >= NT) return;
    float mx = a2[0];
#pragma unroll
    for (int r = 1; r < 8; ++r) mx = fmaxf(mx, a2[r]);
    float sm = 0.f;
#pragma unroll
    for (int r = 0; r < 8; ++r) { a2[r] = __expf(a2[r] - mx); sm += a2[r]; }
    float inv = 1.0f / sm;
#pragma unroll
    for (int r = 0; r < 8; ++r) a2[r] *= inv;
    float4* o1 = reinterpret_cast<float4*>(l1 + (size_t)p * 8);
    float4* o2 = reinterpret_cast<float4*>(l2 + (size_t)p * 8);
    o1[0] = make_float4(a1[0], a1[1], a1[2], a1[3]);
    o1[1] = make_float4(a1[4], a1[5], a1[6], a1[7]);
    o2[0] = make_float4(a2[0], a2[1], a2[2], a2[3]);
    o2[1] = make_float4(a2[4], a2[5], a2[6], a2[7]);
}

// ---------------- CSR offsets (hrow sorted by np.unique) ----------------
__global__ __launch_bounds__(256) void k_rowptr(
    const int* __restrict__ hrow, int* __restrict__ rowptr)
{
    int i = blockIdx.x * blockDim.x + threadIdx.x;
    if (i > NN) return;
    int lo = 0, hi = NT;
    while (lo < hi) { int mid = (lo + hi) >> 1; if (hrow[mid] < i) lo = mid + 1; else hi = mid; }
    rowptr[i] = lo;
}

// ---------------- CSC build ----------------
__global__ __launch_bounds__(256) void k_hist(
    const int* __restrict__ vcol, int* __restrict__ cnt)
{
    int p = blockIdx.x * blockDim.x + threadIdx.x;
    if (p < NT) atomicAdd(&cnt[vcol[p]], 1);
}

__global__ __launch_bounds__(1024) void k_scan(
    const int* __restrict__ cnt, int* __restrict__ cstart, int* __restrict__ cnt2)
{
    __shared__ int part[1024];
    int t = threadIdx.x;
    int base = t * 20;
    int local[20];
    int s = 0;
#pragma unroll
    for (int i = 0; i < 20; ++i) {
        int idx = base + i;
        int c = (idx < NN) ? cnt[idx] : 0;
        local[i] = s;
        s += c;
    }
    part[t] = s;
    __syncthreads();
    for (int off = 1; off < 1024; off <<= 1) {
        int v = (t >= off) ? part[t - off] : 0;
        __syncthreads();
        part[t] += v;
        __syncthreads();
    }
    int ebase = t ? part[t - 1] : 0;
#pragma unroll
    for (int i = 0; i < 20; ++i) {
        int idx = base + i;
        if (idx < NN) { cstart[idx] = ebase + local[i]; cnt2[idx] = ebase + local[i]; }
    }
    if (t == 1023) cstart[NN] = part[1023];
}

__global__ __launch_bounds__(256) void k_pos(
    const int* __restrict__ vcol, int* __restrict__ cnt2, int* __restrict__ cscidx)
{
    int p = blockIdx.x * blockDim.x + threadIdx.x;
    if (p >= NT) return;
    int o = vcol[p];
    int slot = atomicAdd(&cnt2[o], 1);
    cscidx[slot] = p;
}

// ---------------- colsum via CSC gather-reduce ----------------
__global__ __launch_bounds__(256) void k_colsum(
    const float* __restrict__ l1, const int* __restrict__ cstart,
    const int* __restrict__ cscidx, float* __restrict__ colsum)
{
    int bid = blockIdx.x;
    if (bid < COLB) {
        int tid = bid * 256 + threadIdx.x;
        if (tid < NN * 7) {
            int o = tid / 7;
            int r = tid - o * 7 + 1;
            int qb = cstart[o], qe = cstart[o + 1];
            float s = 0.f;
            for (int q = qb; q < qe; ++q)
                s += l1[(size_t)cscidx[q] * 8 + r];
            atomicAdd(&colsum[o * r], s);
        }
    } else {
        int b2 = bid - COLB;
        float s = 0.f;
        for (int i = b2 * 256 + threadIdx.x; i < NT; i += REDB * 256) s += l1[(size_t)i * 8];
        __shared__ float red[256];
        red[threadIdx.x] = s;
        __syncthreads();
        for (int off = 128; off > 0; off >>= 1) {
            if (threadIdx.x < off) red[threadIdx.x] += red[threadIdx.x + off];
            __syncthreads();
        }
        if (threadIdx.x == 0) atomicAdd(&colsum[0], red[0]);
    }
}

// ---------------- invert colsum in place ----------------
__global__ __launch_bounds__(256) void k_inv(float* __restrict__ cs)
{
    int i = blockIdx.x * blockDim.x + threadIdx.x;
    if (i < RP * NN) cs[i] = 1.0f / cs[i];
}

// ---------------- C1: per-object contributions (one wave per o) ----------------
__global__ __launch_bounds__(256) void k_contrib(
    const float* __restrict__ l1, const float* __restrict__ ics,
    const int* __restrict__ cstart, const int* __restrict__ cscidx,
    const float* __restrict__ w1, __half* __restrict__ contrib)
{
    int o = (int)((blockIdx.x * blockDim.x + threadIdx.x) >> 6);
    int lane = threadIdx.x & 63;
    if (o >= NN) return;
    int qb = cstart[o], qe = cstart[o + 1];
    if (qb == qe) return;
    float y[8];
    y[0] = w1[lane] * ics[0];               // seg = o*0 = 0
#pragma unroll
    for (int r = 1; r < 8; ++r) {
        int seg = o * r;
        y[r] = w1[(size_t)seg * EMB + lane] * ics[seg];
    }
    for (int q = qb; q < qe; ++q) {
        int p = cscidx[q];
        const float4* lp4 = reinterpret_cast<const float4*>(l1 + (size_t)p * 8);
        float4 A = lp4[0], B = lp4[1];
        float v = A.x * y[0];
        v = fmaf(A.y, y[1], v); v = fmaf(A.z, y[2], v); v = fmaf(A.w, y[3], v);
        v = fmaf(B.x, y[4], v); v = fmaf(B.y, y[5], v);
        v = fmaf(B.z, y[6], v); v = fmaf(B.w, y[7], v);
        contrib[(size_t)p * EMB + lane] = __float2half(v);
    }
}

// ---------------- C2 (fused): h = relu(bias + sum contrib)  +  rowsum pre-pass ----------------
// prs lane layout: lane = g*8 + r; reads l2[pb*8 + lane + 64t] fully coalesced.
__global__ __launch_bounds__(256) void k_h(
    const __half* __restrict__ contrib, const float* __restrict__ l2,
    const int* __restrict__ rowptr, const float* __restrict__ bias1,
    __half* __restrict__ h, float* __restrict__ rowsum, float* __restrict__ rs0part)
{
    int s = (int)((blockIdx.x * blockDim.x + threadIdx.x) >> 6);
    int lane = threadIdx.x & 63;
    if (s >= NN) return;
    int pb = rowptr[s], pe = rowptr[s + 1];
    float acc = 0.f;
    for (int p = pb; p < pe; ++p)
        acc += __half2float(contrib[(size_t)p * EMB + lane]);
    h[(size_t)s * EMB + lane] = __float2half(fmaxf(acc + bias1[lane], 0.f));

    // rowsum partials: prs[r] = sum_p l2[p][r]
    float psum = 0.f;
    for (int p0 = pb + (lane >> 3); p0 < pe; p0 += 8)
        psum += l2[(size_t)p0 * 8 + (lane & 7)];
    psum += __shfl_xor(psum, 8, 64);
    psum += __shfl_xor(psum, 16, 64);
    psum += __shfl_xor(psum, 32, 64);   // lanes with same (lane&7) now hold prs[r]
    if (s == 0) {
        float tt = psum;
        tt += __shfl_xor(tt, 1, 64);
        tt += __shfl_xor(tt, 2, 64);
        tt += __shfl_xor(tt, 4, 64);
        if (lane == 0) rs0part[0] = tt;          // all 8 r's -> k=0
    } else {
        if (lane == 0) rs0part[s] = psum;        // r=0 -> k=0 partial
        else if (lane < 8) atomicAdd(&rowsum[s * lane], psum);   // k = s*r >= 1
    }
}

// ---------------- reduce rs0part -> irs[0] (stored inverted into rowsum[0]) ----------------
__global__ __launch_bounds__(256) void k_redrs(
    const float* __restrict__ rs0part, float* __restrict__ rowsum)
{
    __shared__ float red[256];
    float sv = 0.f;
    for (int i = threadIdx.x; i < NN; i += 256) sv += rs0part[i];
    red[threadIdx.x] = sv;
    __syncthreads();
    for (int off = 128; off > 0; off >>= 1) {
        if (threadIdx.x < off) red[threadIdx.x] += red[threadIdx.x + off];
        __syncthreads();
    }
    if (threadIdx.x == 0) rowsum[0] = 1.0f / fmaxf(red[0], 1e-6f);
}

// ---------------- invert rowsum[1..KMAX) in place ----------------
__global__ __launch_bounds__(256) void k_inv2(float* __restrict__ rs)
{
    int i = blockIdx.x * blockDim.x + threadIdx.x;
    if (i >= 1 && i < KMAX) rs[i] = 1.0f / fmaxf(rs[i], 1e-6f);
}

// ---------------- init logits with bias2 ----------------
__global__ __launch_bounds__(256) void k_outinit(
    float* __restrict__ out, const float* __restrict__ b2)
{
    int i = blockIdx.x * blockDim.x + threadIdx.x;
    if (i < NN * NCLS) out[i] = b2[i & (NCLS - 1)];
}

// ---------------- D+E fused: per-s acc -> direct logits contribution ----------------
// (division by rowsum distributes over colliding (s,rr) -> no h2 materialization)
__global__ __launch_bounds__(256) void k_l2out(
    const float* __restrict__ l2, const int* __restrict__ rowptr,
    const int* __restrict__ vcol, const __half* __restrict__ h,
    const float* __restrict__ irs, const float* __restrict__ w2,
    float* __restrict__ out, float* __restrict__ Abuf0)
{
    int s = (int)((blockIdx.x * blockDim.x + threadIdx.x) >> 6);
    int lane = threadIdx.x & 63;
    if (s >= NN) return;
    int pb = rowptr[s], pe = rowptr[s + 1];
    float acc[8];
#pragma unroll
    for (int r = 0; r < 8; ++r) acc[r] = 0.f;
    int p = pb;
    for (; p + 1 < pe; p += 2) {            // unroll-2: two h gathers in flight
        int o0 = vcol[p], o1 = vcol[p + 1];
        float hv0 = __half2float(h[(size_t)o0 * EMB + lane]);
        float hv1 = __half2float(h[(size_t)o1 * EMB + lane]);
        const float4* q4 = reinterpret_cast<const float4*>(l2 + (size_t)p * 8);
        float4 A = q4[0], B = q4[1], C = q4[2], D = q4[3];
        acc[0] = fmaf(A.x, hv0, fmaf(C.x, hv1, acc[0]));
        acc[1] = fmaf(A.y, hv0, fmaf(C.y, hv1, acc[1]));
        acc[2] = fmaf(A.z, hv0, fmaf(C.z, hv1, acc[2]));
        acc[3] = fmaf(A.w, hv0, fmaf(C.w, hv1, acc[3]));
        acc[4] = fmaf(B.x, hv0, fmaf(D.x, hv1, acc[4]));
        acc[5] = fmaf(B.y, hv0, fmaf(D.y, hv1, acc[5]));
        acc[6] = fmaf(B.z, hv0, fmaf(D.z, hv1, acc[6]));
        acc[7] = fmaf(B.w, hv0, fmaf(D.w, hv1, acc[7]));
    }
    if (p < pe) {
        int o0 = vcol[p];
        float hv0 = __half2float(h[(size_t)o0 * EMB + lane]);
        const float4* q4 = reinterpret_cast<const float4*>(l2 + (size_t)p * 8);
        float4 A = q4[0], B = q4[1];
        acc[0] = fmaf(A.x, hv0, acc[0]); acc[1] = fmaf(A.y, hv0, acc[1]);
        acc[2] = fmaf(A.z, hv0, acc[2]); acc[3] = fmaf(A.w, hv0, acc[3]);
        acc[4] = fmaf(B.x, hv0, acc[4]); acc[5] = fmaf(B.y, hv0, acc[5]);
        acc[6] = fmaf(B.z, hv0, acc[6]); acc[7] = fmaf(B.w, hv0, acc[7]);
    }
    if (s == 0) {                            // all 8 r's -> k=0: park in Abuf0[0]
        float a = acc[0] + acc[1] + acc[2] + acc[3] +
                  acc[4] + acc[5] + acc[6] + acc[7];
        Abuf0[lane] = a;
        return;
    }
    Abuf0[(size_t)s * EMB + lane] = acc[0];  // r=0 -> k=0 partial (plain store)
    if (pb == pe) return;                    // empty: zeros parked, nothing to add
    int hq = lane >> 4, c = lane & 15;
#pragma unroll
    for (int rr = 1; rr < 8; ++rr) {
        int k = s * rr;                      // 1..139993
        int rp = k / NN;
        int n  = k - rp * NN;
        float sc = irs[k];
        float v = 0.f;
#pragma unroll
        for (int hh = 0; hh < 16; ++hh) {
            float av = __shfl(acc[rr], hq * 16 + hh, 64);
            v = fmaf(av, w2[((rp * EMB) + (hq * 16 + hh)) * NCLS + c], v);
        }
        v += __shfl_xor(v, 16, 64);
        v += __shfl_xor(v, 32, 64);
        if (lane < 16) atomicAdd(&out[(size_t)n * NCLS + lane], v * sc);
    }
}

// ---------------- reduce Abuf0 -> h0row ----------------
__global__ __launch_bounds__(256) void k_redA(
    const float* __restrict__ Abuf0, float* __restrict__ h0row)
{
    __shared__ float red[256];
    int lane = threadIdx.x & 63, w = threadIdx.x >> 6;
    float sum = 0.f;
    for (int ss = blockIdx.x + 64 * w; ss < NN; ss += 256)
        sum += Abuf0[(size_t)ss * EMB + lane];
    red[threadIdx.x] = sum;
    __syncthreads();
    if (threadIdx.x < 64) {
        float v = red[threadIdx.x] + red[threadIdx.x + 64] +
                  red[threadIdx.x + 128] + red[threadIdx.x + 192];
        atomicAdd(&h0row[threadIdx.x], v);
    }
}

// ---------------- k=0 logits contribution (n=0, rp=0) ----------------
__global__ __launch_bounds__(64) void k_out0(
    const float* __restrict__ h0row, const float* __restrict__ irs,
    const float* __restrict__ w2, float* __restrict__ out)
{
    int hq = threadIdx.x >> 4, c = threadIdx.x & 15;
    float v = 0.f;
#pragma unroll
    for (int hh = 0; hh < 16; ++hh) {
        int hd = hq * 16 + hh;
        v = fmaf(h0row[hd], w2[hd * NCLS + c], v);
    }
    v += __shfl_xor(v, 16, 64);
    v += __shfl_xor(v, 32, 64);
    if (threadIdx.x < 16) atomicAdd(&out[c], v * irs[0]);
}

extern "C" void kernel_launch(void* const* d_in, const int* in_sizes, int n_in,
                              void* d_out, int out_size, void* d_ws, size_t ws_size,
                              hipStream_t stream)
{
    const float* rm    = (const float*)d_in[0];
    const int*   hrow  = (const int*)d_in[1];   // sorted source nodes
    const int*   vcol  = (const int*)d_in[4];   // object nodes
    const float* W1    = (const float*)d_in[5];
    const float* b1    = (const float*)d_in[6];
    const float* W2    = (const float*)d_in[7];
    const float* b2    = (const float*)d_in[8];
    const float* w1    = (const float*)d_in[9];
    const float* w2    = (const float*)d_in[10];
    const float* bias1 = (const float*)d_in[11];
    const float* bias2 = (const float*)d_in[12];
    float* out = (float*)d_out;

    float* ws = (float*)d_ws;
    float*  l1      = ws;                       // [0, 2.00M)
    float*  l2      = ws + 2000000;             // [2.00M, 4.00M)
    int*    rowptr  = (int*)(ws + 4000000);     // 20,001 ints
    float*  h0row   = ws + 4030000;             // 64
    float*  colsum  = ws + 4100000;             // 160,000 (inverted in place)
    float*  rowsum  = ws + 4260000;             // 140,000 (inverted in place)
    __half* h       = (__half*)(ws + 4400000);  // 1.28M halfs = 640K slots [4.40M, 5.04M)
    // CSC scratch: placed AFTER h region would clash; put in [5.04M, 5.40M)
    int*    cnt     = (int*)(ws + 5040000);     // 20,000
    int*    cstart  = cnt + 20000;              // 20,001
    int*    cnt2    = cstart + 20001;           // 20,000
    int*    cscidx  = cnt2 + 20000;             // 250,000 (ends 5.35M)
    __half* contrib = (__half*)(ws + 5600000);  // 16M halfs [5.60M, 13.60M)
    // Abuf0/rs0part overlay l1 (l1 dead after k_contrib)
    float*  Abuf0   = ws;                       // 1.28M
    float*  rs0part = ws + 1280000;             // 20,000

    hipMemsetAsync(colsum, 0, (size_t)160000 * sizeof(float), stream);
    hipMemsetAsync(rowsum, 0, (size_t)KMAX * sizeof(float), stream);
    hipMemsetAsync(h0row, 0, (size_t)64 * sizeof(float), stream);
    hipMemsetAsync(cnt, 0, (size_t)20000 * sizeof(int), stream);

    k_rowptr <<<(NN + 256) / 256, 256, 0, stream>>>(hrow, rowptr);
    k_hist   <<<(NT + 255) / 256, 256, 0, stream>>>(vcol, cnt);
    k_scan   <<<1, 1024, 0, stream>>>(cnt, cstart, cnt2);
    k_pos    <<<(NT + 255) / 256, 256, 0, stream>>>(vcol, cnt2, cscidx);
    k_gemv   <<<(NT + 255) / 256, 256, 0, stream>>>(rm, W1, b1, W2, b2, l1, l2);
    k_colsum <<<COLB + REDB, 256, 0, stream>>>(l1, cstart, cscidx, colsum);
    k_inv    <<<(RP * NN + 255) / 256, 256, 0, stream>>>(colsum);
    k_contrib<<<(NN * 64) / 256, 256, 0, stream>>>(l1, colsum, cstart, cscidx, w1, contrib);
    k_h      <<<(NN * 64) / 256, 256, 0, stream>>>(contrib, l2, rowptr, bias1, h, rowsum, rs0part);
    k_redrs  <<<1, 256, 0, stream>>>(rs0part, rowsum);
    k_inv2   <<<(KMAX + 255) / 256, 256, 0, stream>>>(rowsum);
    k_outinit<<<(NN * NCLS + 255) / 256, 256, 0, stream>>>(out, bias2);
    k_l2out  <<<(NN * 64) / 256, 256, 0, stream>>>(l2, rowptr, vcol, h, rowsum, w2, out, Abuf0);
    k_redA   <<<64, 256, 0, stream>>>(Abuf0, h0row);
    k_out0   <<<1, 64, 0, stream>>>(h0row, rowsum, w2, out);
}